// Round 8
// baseline (303.814 us; speedup 1.0000x reference)
//
#include <hip/hip_runtime.h>
#include <hip/hip_cooperative_groups.h>
#include <math.h>

namespace cg = cooperative_groups;

#define NN 4096
#define MM 32
#define LOG2F_ 0.69314718055994530942f

typedef __attribute__((ext_vector_type(8))) short short8;
typedef __attribute__((ext_vector_type(4))) float f32x4;

__device__ __forceinline__ float ssp_fast(float x) {
    float sp = (x > 20.0f) ? x : __logf(1.0f + __expf(x));
    return sp - LOG2F_;
}

// float -> bf16 bits, round-to-nearest-even
__device__ __forceinline__ short f2bf(float x) {
    unsigned u = __float_as_uint(x);
    unsigned r = (u + 0x7FFFu + ((u >> 16) & 1u)) >> 16;
    return (short)r;
}
__device__ __forceinline__ float bf2f(short s) {
    return __uint_as_float(((unsigned)(unsigned short)s) << 16);
}

// mode 0: phase A + grid.sync + phase B  (cooperative launch)
// mode 1: phase A only                    (fallback launch 1)
// mode 2: phase B only                    (fallback launch 2)
// All phases are grid-stride, so any grid size is correct.
__global__ __launch_bounds__(256, 4) void se3_kernel(
    const float* __restrict__ xyz, const float* __restrict__ feat,
    const float* __restrict__ w_f1, const float* __restrict__ w_f2,
    const float* __restrict__ w_pre0, const float* __restrict__ w_pre1,
    const float* __restrict__ w_a0, const float* __restrict__ w_a1,
    const float* __restrict__ w_b0, const float* __restrict__ w_b1,
    const int* __restrict__ src_idx, const int* __restrict__ edge_mask,
    float* __restrict__ pre_t, float* __restrict__ out, int mode)
{
    int t = threadIdx.x;
    int lane = t & 63, wave = t >> 6, q = lane >> 4, nn = lane & 15;

    __shared__ __align__(16) short s_rbf[64 * 40];  // ph.A: feat A tiles
    __shared__ __align__(16) short s_h[64 * 72];    // ph.A: w_pre0^T
    __shared__ __align__(16) short s_f[64 * 72];    // ph.A: w_pre1^T
    __shared__ __align__(16) float s_geo[64 * 4];   // {ry, rz, rx, mask}
    __shared__ float s_xs[64 * 2];                  // {x, env/d}
    __shared__ int   s_ji[64];
    __shared__ __align__(16) float s_agg[2 * 704];  // ph.A: staged pre out

    // ================= Phase A: pre = ielin(feat, w_pre) =================
    if (mode != 2) {
        short* s_w0p = s_h;
        short* s_w1p = s_f;
        short* s_pa0 = s_rbf;               // l0 A tile 16x72 (rows 0-3)
        short* s_pa1 = s_rbf + 16 * 72;     // l1 A tile 16x72 (rows 0-11)
        float* s_po  = s_agg;               // 4 x 256 staged output

        // stage w_pre^T -> bf16 (once; persists across node groups)
        #pragma unroll 4
        for (int kk = 0; kk < 16; ++kk) {
            int k = wave * 16 + kk;
            s_w0p[lane * 72 + k] = f2bf(w_pre0[k * 64 + lane]);
            s_w1p[lane * 72 + k] = f2bf(w_pre1[k * 64 + lane]);
        }
        // zero pad rows once (never overwritten by feat fill)
        for (int idx = t; idx < 768; idx += 256) {
            int r = 4 + (idx >> 6), k = idx & 63;
            s_pa0[r * 72 + k] = 0;
        }
        {
            int r = 12 + (t >> 6), k = t & 63;
            s_pa1[r * 72 + k] = 0;
        }
        __syncthreads();

        short8 bw0[2], bw1[2];
        #pragma unroll
        for (int kc = 0; kc < 2; ++kc) {
            bw0[kc] = *(const short8*)&s_w0p[(16 * wave + nn) * 72 + kc * 32 + q * 8];
            bw1[kc] = *(const short8*)&s_w1p[(16 * wave + nn) * 72 + kc * 32 + q * 8];
        }
        int col = 16 * wave + nn;

        for (int nb = blockIdx.x; nb < NN / 4; nb += gridDim.x) {
            int base4 = nb * 4;
            // fill feat -> bf16 A tiles (4 nodes x 256 floats)
            {
                float4 v = ((const float4*)(feat + (size_t)base4 * 256))[t];
                int node = t >> 6, c = (t & 63) * 4;
                short* dst;
                if (c < 64) {
                    dst = &s_pa0[node * 72 + c];
                } else {
                    int mmi = (c >> 6) - 1;
                    int row = node * 3 + mmi;
                    dst = &s_pa1[row * 72 + (c & 63)];
                }
                dst[0] = f2bf(v.x); dst[1] = f2bf(v.y);
                dst[2] = f2bf(v.z); dst[3] = f2bf(v.w);
            }
            __syncthreads();
            // l0: rows = nodes 0..3
            {
                f32x4 acc = {0.f, 0.f, 0.f, 0.f};
                #pragma unroll
                for (int kc = 0; kc < 2; ++kc) {
                    short8 a = *(const short8*)&s_pa0[nn * 72 + kc * 32 + q * 8];
                    acc = __builtin_amdgcn_mfma_f32_16x16x32_bf16(a, bw0[kc], acc, 0, 0, 0);
                }
                if (q == 0) {
                    #pragma unroll
                    for (int r = 0; r < 4; ++r)
                        s_po[r * 256 + col * 4 + 0] = acc[r];
                }
            }
            // l1: rows = node*3 + m, 0..11
            {
                f32x4 acc = {0.f, 0.f, 0.f, 0.f};
                #pragma unroll
                for (int kc = 0; kc < 2; ++kc) {
                    short8 a = *(const short8*)&s_pa1[nn * 72 + kc * 32 + q * 8];
                    acc = __builtin_amdgcn_mfma_f32_16x16x32_bf16(a, bw1[kc], acc, 0, 0, 0);
                }
                #pragma unroll
                for (int r = 0; r < 4; ++r) {
                    int row = 4 * q + r;
                    if (row < 12) {
                        int node = (int)((unsigned)row / 3u);
                        int mmi = row - node * 3;
                        s_po[node * 256 + col * 4 + 1 + mmi] = acc[r];
                    }
                }
            }
            __syncthreads();
            *(float4*)&pre_t[(size_t)base4 * 256 + t * 4] = *(const float4*)&s_po[t * 4];
            __syncthreads();
        }
    }

    if (mode == 0) cg::this_grid().sync();
    if (mode == 1) return;

    // radial-MLP B fragments straight from global weights (L2-hot)
    short8 b1, b2_0, b2_1;
    {
        int col = 16 * wave + nn;
        #pragma unroll
        for (int j = 0; j < 8; ++j) {
            int k1 = q * 8 + j;
            b1[j]   = (k1 < 16) ? f2bf(w_f1[k1 * 64 + col]) : (short)0;
            b2_0[j] = f2bf(w_f2[k1 * 64 + col]);
            b2_1[j] = f2bf(w_f2[(32 + k1) * 64 + col]);
        }
    }

    // ================= Phase B: edge processing =================
    for (int bi = blockIdx.x; bi < NN / 2; bi += gridDim.x) {
        __syncthreads();   // protect LDS reuse across iterations/phases
        int i0 = bi * 2;

        for (int k = t; k < 1408; k += 256) s_agg[k] = 0.f;
        for (int idx = t; idx < 1024; idx += 256) {   // zero K-pad cols 16..31
            int e = idx >> 4, k = 16 + (idx & 15);
            s_rbf[e * 40 + k] = 0;
        }

        if (t < 64) {
            int node = t >> 5, e = t & 31;
            int i = i0 + node;
            int j = src_idx[i * MM + e];
            float msk = (float)edge_mask[i * MM + e];
            float r0 = xyz[j * 3 + 0] - xyz[i * 3 + 0];
            float r1 = xyz[j * 3 + 1] - xyz[i * 3 + 1];
            float r2 = xyz[j * 3 + 2] - xyz[i * 3 + 2];
            float d = sqrtf(r0 * r0 + r1 * r1 + r2 * r2);
            float inv_d = 1.0f / d;
            float x = d * 0.2f;
            float env = 0.f;
            if (x < 1.f) {
                float x3 = x * x * x;
                env = 1.f - 10.f * x3 + 15.f * x3 * x - 6.f * x3 * x * x;
            }
            s_geo[t * 4 + 0] = r1 * inv_d;
            s_geo[t * 4 + 1] = r2 * inv_d;
            s_geo[t * 4 + 2] = r0 * inv_d;
            s_geo[t * 4 + 3] = msk;
            s_xs[t * 2 + 0] = x;
            s_xs[t * 2 + 1] = env * inv_d;
            s_ji[t] = j;
        }
        __syncthreads();

        #pragma unroll
        for (int rep = 0; rep < 4; ++rep) {           // 1024 sins
            int idx = t + rep * 256;
            int e = idx >> 4, k = idx & 15;
            s_rbf[e * 40 + k] = f2bf(__sinf(s_xs[e * 2] * (float)k) * s_xs[e * 2 + 1]);
        }
        __syncthreads();

        // P2: h = ssp(rbf @ w1)
        {
            f32x4 z = {0.f, 0.f, 0.f, 0.f};
            #pragma unroll
            for (int mt = 0; mt < 4; ++mt) {
                short8 a = *(const short8*)&s_rbf[(16 * mt + nn) * 40 + q * 8];
                f32x4 h = __builtin_amdgcn_mfma_f32_16x16x32_bf16(a, b1, z, 0, 0, 0);
                #pragma unroll
                for (int r = 0; r < 4; ++r)
                    s_h[(16 * mt + 4 * q + r) * 72 + 16 * wave + nn] = f2bf(ssp_fast(h[r]));
            }
        }
        __syncthreads();

        // P3: fr = h @ w2
        {
            #pragma unroll
            for (int mt = 0; mt < 4; ++mt) {
                f32x4 acc = {0.f, 0.f, 0.f, 0.f};
                short8 a0 = *(const short8*)&s_h[(16 * mt + nn) * 72 + q * 8];
                acc = __builtin_amdgcn_mfma_f32_16x16x32_bf16(a0, b2_0, acc, 0, 0, 0);
                short8 a1 = *(const short8*)&s_h[(16 * mt + nn) * 72 + 32 + q * 8];
                acc = __builtin_amdgcn_mfma_f32_16x16x32_bf16(a1, b2_1, acc, 0, 0, 0);
                #pragma unroll
                for (int r = 0; r < 4; ++r)
                    s_f[(16 * mt + 4 * q + r) * 72 + 16 * wave + nn] = f2bf(acc[r]);
            }
        }
        __syncthreads();

        // P4: coupling; wave -> 16 edges of node (wave>>1); lane == channel
        {
            int ebase = wave * 16;
            float acc0a = 0.f, acc0b = 0.f;
            float P01[3] = {0.f, 0.f, 0.f};
            float P10[3] = {0.f, 0.f, 0.f};
            float P11[3] = {0.f, 0.f, 0.f};
            float4 pv[2][4];

            #pragma unroll
            for (int u = 0; u < 4; ++u)
                pv[0][u] = ((const float4*)pre_t)[(size_t)s_ji[ebase + u] * 64 + lane];

            #pragma unroll
            for (int bb = 0; bb < 16; bb += 4) {
                int cur = (bb >> 2) & 1, nxt = cur ^ 1;
                if (bb < 12) {
                    #pragma unroll
                    for (int u = 0; u < 4; ++u)
                        pv[nxt][u] = ((const float4*)pre_t)[(size_t)s_ji[ebase + bb + 4 + u] * 64 + lane];
                }
                #pragma unroll
                for (int u = 0; u < 4; ++u) {
                    int e = ebase + bb + u;
                    float4 g = *(const float4*)&s_geo[e * 4];
                    float ry = g.x, rz = g.y, rx = g.z;
                    float f = bf2f(s_f[e * 72 + lane]) * g.w;
                    float a0 = pv[cur][u].x, a1y = pv[cur][u].y;
                    float a1z = pv[cur][u].z, a1x = pv[cur][u].w;

                    float a0f = a0 * f;
                    acc0a += a0f;
                    acc0b = fmaf(f, a1y * ry + a1z * rz + a1x * rx, acc0b);
                    P01[0] = fmaf(a0f, ry, P01[0]);
                    P01[1] = fmaf(a0f, rz, P01[1]);
                    P01[2] = fmaf(a0f, rx, P01[2]);
                    P10[0] = fmaf(a1y, f, P10[0]);
                    P10[1] = fmaf(a1z, f, P10[1]);
                    P10[2] = fmaf(a1x, f, P10[2]);
                    P11[0] = fmaf(a1z * rx - a1x * rz, f, P11[0]);  // cy
                    P11[1] = fmaf(a1x * ry - a1y * rx, f, P11[1]);  // cz
                    P11[2] = fmaf(a1y * rz - a1z * ry, f, P11[2]);  // cx
                }
            }

            float* agg = &s_agg[(wave >> 1) * 704];
            atomicAdd(&agg[lane], acc0a);
            atomicAdd(&agg[64 + lane], acc0b);
            #pragma unroll
            for (int m = 0; m < 3; ++m) {
                atomicAdd(&agg[128 + m * 192 + lane], P01[m]);
                atomicAdd(&agg[128 + m * 192 + 64 + lane], P10[m]);
                atomicAdd(&agg[128 + m * 192 + 128 + lane], P11[m]);
            }
        }
        __syncthreads();

        // P5: fused finish; s_cout/s_gated alias dead s_h
        float* s_cout  = (float*)s_h;
        float* s_gated = ((float*)s_h) + 512;

        {
            const float* w = (wave == 0) ? w_a0 : w_a1;
            int K4 = (wave == 0) ? 32 : 48;
            int aoff = (wave == 0) ? 0 : 128 + (wave - 1) * 192;
            float acc0 = 0.f, acc1 = 0.f;
            for (int c4 = 0; c4 < K4; ++c4) {
                int c = c4 * 4;
                float wx = w[(c + 0) * 64 + lane];
                float wy = w[(c + 1) * 64 + lane];
                float wz = w[(c + 2) * 64 + lane];
                float ww = w[(c + 3) * 64 + lane];
                float4 a0v = *(const float4*)&s_agg[aoff + c];
                float4 a1v = *(const float4*)&s_agg[704 + aoff + c];
                acc0 = fmaf(a0v.x, wx, fmaf(a0v.y, wy, fmaf(a0v.z, wz, fmaf(a0v.w, ww, acc0))));
                acc1 = fmaf(a1v.x, wx, fmaf(a1v.y, wy, fmaf(a1v.z, wz, fmaf(a1v.w, ww, acc1))));
            }
            s_cout[t] = acc0;
            s_cout[256 + t] = acc1;
        }
        __syncthreads();

        #pragma unroll
        for (int n = 0; n < 2; ++n) {
            float v = s_cout[n * 256 + t];
            float g;
            if (wave == 0) {
                g = ssp_fast(v);
            } else {
                float c0 = s_cout[n * 256 + 64 + lane];
                float c1 = s_cout[n * 256 + 128 + lane];
                float c2 = s_cout[n * 256 + 192 + lane];
                g = ssp_fast(sqrtf(fmaf(c0, c0, fmaf(c1, c1, fmaf(c2, c2, 1e-12f)))));
            }
            s_gated[n * 256 + t] = v * g;
        }
        __syncthreads();

        {
            const float* w = (wave == 0) ? w_b0 : w_b1;
            int aoff = (wave == 0) ? 0 : 64 + (wave - 1) * 64;
            float acc0 = 0.f, acc1 = 0.f;
            for (int c4 = 0; c4 < 16; ++c4) {
                int c = c4 * 4;
                float wx = w[(c + 0) * 64 + lane];
                float wy = w[(c + 1) * 64 + lane];
                float wz = w[(c + 2) * 64 + lane];
                float ww = w[(c + 3) * 64 + lane];
                float4 g0 = *(const float4*)&s_gated[aoff + c];
                float4 g1 = *(const float4*)&s_gated[256 + aoff + c];
                acc0 = fmaf(g0.x, wx, fmaf(g0.y, wy, fmaf(g0.z, wz, fmaf(g0.w, ww, acc0))));
                acc1 = fmaf(g1.x, wx, fmaf(g1.y, wy, fmaf(g1.z, wz, fmaf(g1.w, ww, acc1))));
            }
            out[(size_t)i0 * 256 + t]       = feat[(size_t)i0 * 256 + t] + acc0;
            out[(size_t)(i0 + 1) * 256 + t] = feat[(size_t)(i0 + 1) * 256 + t] + acc1;
        }
    }
}

extern "C" void kernel_launch(void* const* d_in, const int* in_sizes, int n_in,
                              void* d_out, int out_size, void* d_ws, size_t ws_size,
                              hipStream_t stream) {
    const float* xyz     = (const float*)d_in[0];
    const float* feat    = (const float*)d_in[1];
    const float* w_f1    = (const float*)d_in[2];
    const float* w_f2    = (const float*)d_in[3];
    const float* w_pre0  = (const float*)d_in[4];
    const float* w_pre1  = (const float*)d_in[5];
    const float* w_a0    = (const float*)d_in[6];
    const float* w_a1    = (const float*)d_in[7];
    const float* w_b0    = (const float*)d_in[8];
    const float* w_b1    = (const float*)d_in[9];
    const int* src_idx   = (const int*)d_in[10];
    const int* edge_mask = (const int*)d_in[11];
    float* out = (float*)d_out;
    float* pre_t = (float*)d_ws;   // 4 MB

    // size the cooperative grid to the真 co-residency capacity
    int maxb = 0;
    (void)hipOccupancyMaxActiveBlocksPerMultiprocessor(&maxb, se3_kernel, 256, 0);
    int grid = maxb * 256;               // 256 CUs on MI355X
    if (grid > 1024) grid = 1024;

    int mode0 = 0, mode1 = 1, mode2 = 2;
    bool coop_ok = false;
    if (grid >= 256) {
        void* args[] = {
            (void*)&xyz, (void*)&feat, (void*)&w_f1, (void*)&w_f2,
            (void*)&w_pre0, (void*)&w_pre1, (void*)&w_a0, (void*)&w_a1,
            (void*)&w_b0, (void*)&w_b1, (void*)&src_idx, (void*)&edge_mask,
            (void*)&pre_t, (void*)&out, (void*)&mode0
        };
        hipError_t e = hipLaunchCooperativeKernel((void*)se3_kernel, dim3(grid),
                                                  dim3(256), args, 0, stream);
        coop_ok = (e == hipSuccess);
        if (!coop_ok) (void)hipGetLastError();   // clear sticky error
    }
    if (!coop_ok) {
        // fallback: two ordinary launches (phase A, then phase B)
        se3_kernel<<<1024, 256, 0, stream>>>(xyz, feat, w_f1, w_f2, w_pre0,
                                             w_pre1, w_a0, w_a1, w_b0, w_b1,
                                             src_idx, edge_mask, pre_t, out, mode1);
        se3_kernel<<<1024, 256, 0, stream>>>(xyz, feat, w_f1, w_f2, w_pre0,
                                             w_pre1, w_a0, w_a1, w_b0, w_b1,
                                             src_idx, edge_mask, pre_t, out, mode2);
    }
}

// Round 9
// 144.002 us; speedup vs baseline: 2.1098x; 2.1098x over previous
//
#include <hip/hip_runtime.h>
#include <math.h>

#define NN 4096
#define MM 32
#define LOG2F_ 0.69314718055994530942f

typedef __attribute__((ext_vector_type(8))) short short8;
typedef __attribute__((ext_vector_type(4))) float f32x4;

__device__ __forceinline__ float ssp_fast(float x) {
    float sp = (x > 20.0f) ? x : __logf(1.0f + __expf(x));
    return sp - LOG2F_;
}

// float -> bf16 bits, round-to-nearest-even
__device__ __forceinline__ short f2bf(float x) {
    unsigned u = __float_as_uint(x);
    unsigned r = (u + 0x7FFFu + ((u >> 16) & 1u)) >> 16;
    return (short)r;
}
__device__ __forceinline__ float bf2f(short s) {
    return __uint_as_float(((unsigned)(unsigned short)s) << 16);
}

// K1: pre = ielin(feat, w_pre0, w_pre1) via MFMA. 8 nodes/block.
// pre_t[node][ch*4 + p], p = {l0, y, z, x} (float4 per (node,channel)).
// Block 0 also converts w_f1/w_f2 to bf16 B^T layout.
__global__ __launch_bounds__(256) void pre_kernel(
    const float* __restrict__ feat, const float* __restrict__ w0,
    const float* __restrict__ w1, float* __restrict__ pre_t,
    const float* __restrict__ w_f1, const float* __restrict__ w_f2,
    short* __restrict__ w1t, short* __restrict__ w2t)
{
    int t = threadIdx.x;
    int base = blockIdx.x * 8;
    int lane = t & 63, wave = t >> 6, q = lane >> 4, nn = lane & 15;

    if (blockIdx.x == 0) {
        for (int idx = t; idx < 64 * 32; idx += 256) {
            int n = idx >> 5, k = idx & 31;
            w1t[idx] = (k < 16) ? f2bf(w_f1[k * 64 + n]) : (short)0;
        }
        for (int idx = t; idx < 64 * 64; idx += 256) {
            int n = idx >> 6, k = idx & 63;
            w2t[idx] = f2bf(w_f2[k * 64 + n]);
        }
    }

    __shared__ __align__(16) short s_a0[16 * 72];      // l0 feat rows (8 valid)
    __shared__ __align__(16) short s_a1[2][16 * 72];   // l1 feat rows (24 valid)
    __shared__ __align__(16) short s_w0[64 * 72];      // w_pre0^T bf16
    __shared__ __align__(16) short s_w1[64 * 72];      // w_pre1^T bf16
    __shared__ __align__(16) float s_po[8][256];       // staged output

    for (int idx = t; idx < 512; idx += 256) {
        int r = 8 + (idx >> 6), k = idx & 63;
        s_a0[r * 72 + k] = 0;
        s_a1[1][r * 72 + k] = 0;
    }
    #pragma unroll 4
    for (int kk = 0; kk < 16; ++kk) {
        int k = wave * 16 + kk;
        s_w0[lane * 72 + k] = f2bf(w0[k * 64 + lane]);
        s_w1[lane * 72 + k] = f2bf(w1[k * 64 + lane]);
    }
    {
        const float4* f4 = (const float4*)(feat + (size_t)base * 256);
        #pragma unroll
        for (int rep = 0; rep < 2; ++rep) {
            int idx = t + rep * 256;
            float4 v = f4[idx];
            int node = idx >> 6, c = (idx & 63) * 4;
            short* dst;
            if (c < 64) {
                dst = &s_a0[node * 72 + c];
            } else {
                int mm = (c >> 6) - 1, ch = c & 63;
                int row = node * 3 + mm;
                dst = &s_a1[row >> 4][(row & 15) * 72 + ch];
            }
            dst[0] = f2bf(v.x); dst[1] = f2bf(v.y);
            dst[2] = f2bf(v.z); dst[3] = f2bf(v.w);
        }
    }
    __syncthreads();

    short8 bw0[2], bw1[2];
    #pragma unroll
    for (int kc = 0; kc < 2; ++kc) {
        bw0[kc] = *(const short8*)&s_w0[(16 * wave + nn) * 72 + kc * 32 + q * 8];
        bw1[kc] = *(const short8*)&s_w1[(16 * wave + nn) * 72 + kc * 32 + q * 8];
    }

    {
        f32x4 acc = {0.f, 0.f, 0.f, 0.f};
        #pragma unroll
        for (int kc = 0; kc < 2; ++kc) {
            short8 a = *(const short8*)&s_a0[nn * 72 + kc * 32 + q * 8];
            acc = __builtin_amdgcn_mfma_f32_16x16x32_bf16(a, bw0[kc], acc, 0, 0, 0);
        }
        if (q < 2) {
            #pragma unroll
            for (int r = 0; r < 4; ++r) {
                int node = 4 * q + r;
                s_po[node][(16 * wave + nn) * 4 + 0] = acc[r];
            }
        }
    }
    #pragma unroll
    for (int tile = 0; tile < 2; ++tile) {
        f32x4 acc = {0.f, 0.f, 0.f, 0.f};
        #pragma unroll
        for (int kc = 0; kc < 2; ++kc) {
            short8 a = *(const short8*)&s_a1[tile][nn * 72 + kc * 32 + q * 8];
            acc = __builtin_amdgcn_mfma_f32_16x16x32_bf16(a, bw1[kc], acc, 0, 0, 0);
        }
        #pragma unroll
        for (int r = 0; r < 4; ++r) {
            int row = tile * 16 + 4 * q + r;
            if (row < 24) {
                unsigned node = (unsigned)row / 3u;
                int mm = row - (int)node * 3;
                s_po[node][(16 * wave + nn) * 4 + 1 + mm] = acc[r];
            }
        }
    }
    __syncthreads();

    #pragma unroll
    for (int rep = 0; rep < 2; ++rep) {
        int idx = t + rep * 256;
        int node = idx >> 6, c4 = idx & 63;
        *(float4*)&pre_t[(size_t)(base + node) * 256 + c4 * 4] =
            *(const float4*)&s_po[node][c4 * 4];
    }
}

// K2: 2 nodes/block. Geometry lives in registers (4-way redundant per wave,
// readlane broadcasts in P4); first 8 gathers prefetched before the MFMA
// phases; 6 barriers total.
__global__ __launch_bounds__(256, 5) void edge_kernel(
    const float* __restrict__ xyz, const float* __restrict__ feat,
    const float* __restrict__ pre_t,
    const short* __restrict__ w1t_g, const short* __restrict__ w2t_g,
    const float* __restrict__ w_a0, const float* __restrict__ w_a1,
    const float* __restrict__ w_b0, const float* __restrict__ w_b1,
    const int* __restrict__ src_idx, const int* __restrict__ edge_mask,
    float* __restrict__ out)
{
    int bi = blockIdx.x;           // 2048 blocks x 2 nodes
    int i0 = bi * 2;
    int t = threadIdx.x;
    int lane = t & 63;
    int wave = t >> 6;
    int q = lane >> 4;
    int nn = lane & 15;

    __shared__ __align__(16) short s_rbf[64 * 40];  // A tiles, K pad to 32
    __shared__ __align__(16) short s_h[64 * 72];    // hidden; later cout/gated
    __shared__ __align__(16) short s_f[64 * 72];    // filters bf16
    __shared__ __align__(16) float s_agg[2 * 704];

    short8 b1   = *(const short8*)&w1t_g[(16 * wave + nn) * 32 + q * 8];
    short8 b2_0 = *(const short8*)&w2t_g[(16 * wave + nn) * 64 + q * 8];
    short8 b2_1 = *(const short8*)&w2t_g[(16 * wave + nn) * 64 + 32 + q * 8];

    for (int k = t; k < 1408; k += 256) s_agg[k] = 0.f;
    for (int idx = t; idx < 1024; idx += 256) {      // zero K-pad cols 16..31
        int e = idx >> 4, k = 16 + (idx & 15);
        s_rbf[e * 40 + k] = 0;
    }

    // ---- geometry: every lane computes its wave's edge (lane&15) ----
    int e_loc = lane & 15;
    int e_g = 16 * wave + e_loc;                 // block-local edge id 0..63
    int i_node = i0 + (e_g >> 5);
    int edge = e_g & 31;
    int j = src_idx[i_node * MM + edge];
    float msk = (float)edge_mask[i_node * MM + edge];
    float r0 = xyz[j * 3 + 0] - xyz[i_node * 3 + 0];
    float r1 = xyz[j * 3 + 1] - xyz[i_node * 3 + 1];
    float r2 = xyz[j * 3 + 2] - xyz[i_node * 3 + 2];
    float d = sqrtf(r0 * r0 + r1 * r1 + r2 * r2);
    float inv_d = 1.0f / d;
    float x = d * 0.2f;
    float env = 0.f;
    if (x < 1.f) {
        float x3 = x * x * x;
        env = 1.f - 10.f * x3 + 15.f * x3 * x - 6.f * x3 * x * x;
    }
    float sc = env * inv_d;
    float ry = r1 * inv_d, rz = r2 * inv_d, rx = r0 * inv_d;

    // ---- prefetch first 8 edges' pre rows (SGPR base via readlane) ----
    float4 pv[2][4];
    #pragma unroll
    for (int u = 0; u < 4; ++u) {
        int ju = __shfl(j, u, 64);
        pv[0][u] = ((const float4*)pre_t)[(size_t)ju * 64 + lane];
    }
    #pragma unroll
    for (int u = 0; u < 4; ++u) {
        int ju = __shfl(j, 4 + u, 64);
        pv[1][u] = ((const float4*)pre_t)[(size_t)ju * 64 + lane];
    }

    // ---- sins: 4 per lane (own edge, k = 4*(lane>>4)+jj) ----
    {
        float kbase = (float)(4 * (lane >> 4));
        #pragma unroll
        for (int jj = 0; jj < 4; ++jj)
            s_rbf[e_g * 40 + 4 * (lane >> 4) + jj] =
                f2bf(__sinf(x * (kbase + (float)jj)) * sc);
    }
    __syncthreads();

    // P2: h = ssp(rbf @ w1)
    {
        f32x4 z = {0.f, 0.f, 0.f, 0.f};
        #pragma unroll
        for (int mt = 0; mt < 4; ++mt) {
            short8 a = *(const short8*)&s_rbf[(16 * mt + nn) * 40 + q * 8];
            f32x4 h = __builtin_amdgcn_mfma_f32_16x16x32_bf16(a, b1, z, 0, 0, 0);
            #pragma unroll
            for (int r = 0; r < 4; ++r)
                s_h[(16 * mt + 4 * q + r) * 72 + 16 * wave + nn] = f2bf(ssp_fast(h[r]));
        }
    }
    __syncthreads();

    // P3: fr = h @ w2
    {
        #pragma unroll
        for (int mt = 0; mt < 4; ++mt) {
            f32x4 acc = {0.f, 0.f, 0.f, 0.f};
            short8 a0 = *(const short8*)&s_h[(16 * mt + nn) * 72 + q * 8];
            acc = __builtin_amdgcn_mfma_f32_16x16x32_bf16(a0, b2_0, acc, 0, 0, 0);
            short8 a1 = *(const short8*)&s_h[(16 * mt + nn) * 72 + 32 + q * 8];
            acc = __builtin_amdgcn_mfma_f32_16x16x32_bf16(a1, b2_1, acc, 0, 0, 0);
            #pragma unroll
            for (int r = 0; r < 4; ++r)
                s_f[(16 * mt + 4 * q + r) * 72 + 16 * wave + nn] = f2bf(acc[r]);
        }
    }
    __syncthreads();

    // P4: coupling; wave -> its 16 edges; lane == channel.
    {
        int ebase = wave * 16;
        float acc0a = 0.f, acc0b = 0.f;
        float P01[3] = {0.f, 0.f, 0.f};
        float P10[3] = {0.f, 0.f, 0.f};
        float P11[3] = {0.f, 0.f, 0.f};

        #pragma unroll
        for (int g = 0; g < 4; ++g) {
            float4 nx[4];
            if (g < 2) {
                #pragma unroll
                for (int u = 0; u < 4; ++u) {
                    int jn = __shfl(j, (g + 2) * 4 + u, 64);
                    nx[u] = ((const float4*)pre_t)[(size_t)jn * 64 + lane];
                }
            }
            #pragma unroll
            for (int u = 0; u < 4; ++u) {
                int el = g * 4 + u;
                float ryu = __shfl(ry, el, 64);
                float rzu = __shfl(rz, el, 64);
                float rxu = __shfl(rx, el, 64);
                float msku = __shfl(msk, el, 64);
                float f = bf2f(s_f[(ebase + el) * 72 + lane]) * msku;
                float a0 = pv[g & 1][u].x, a1y = pv[g & 1][u].y;
                float a1z = pv[g & 1][u].z, a1x = pv[g & 1][u].w;

                float a0f = a0 * f;
                acc0a += a0f;
                acc0b = fmaf(f, a1y * ryu + a1z * rzu + a1x * rxu, acc0b);
                P01[0] = fmaf(a0f, ryu, P01[0]);
                P01[1] = fmaf(a0f, rzu, P01[1]);
                P01[2] = fmaf(a0f, rxu, P01[2]);
                P10[0] = fmaf(a1y, f, P10[0]);
                P10[1] = fmaf(a1z, f, P10[1]);
                P10[2] = fmaf(a1x, f, P10[2]);
                P11[0] = fmaf(a1z * rxu - a1x * rzu, f, P11[0]);  // cy
                P11[1] = fmaf(a1x * ryu - a1y * rxu, f, P11[1]);  // cz
                P11[2] = fmaf(a1y * rzu - a1z * ryu, f, P11[2]);  // cx
            }
            if (g < 2) {
                #pragma unroll
                for (int u = 0; u < 4; ++u) pv[g & 1][u] = nx[u];
            }
        }

        float* agg = &s_agg[(wave >> 1) * 704];
        atomicAdd(&agg[lane], acc0a);
        atomicAdd(&agg[64 + lane], acc0b);
        #pragma unroll
        for (int m = 0; m < 3; ++m) {
            atomicAdd(&agg[128 + m * 192 + lane], P01[m]);
            atomicAdd(&agg[128 + m * 192 + 64 + lane], P10[m]);
            atomicAdd(&agg[128 + m * 192 + 128 + lane], P11[m]);
        }
    }
    __syncthreads();

    // P5: fused finish; s_cout/s_gated alias dead s_h
    float* s_cout  = (float*)s_h;          // 2 x 256 floats
    float* s_gated = ((float*)s_h) + 512;  // 2 x 256 floats

    {
        const float* w = (wave == 0) ? w_a0 : w_a1;
        int K4 = (wave == 0) ? 32 : 48;
        int aoff = (wave == 0) ? 0 : 128 + (wave - 1) * 192;
        float acc0 = 0.f, acc1 = 0.f;
        for (int c4 = 0; c4 < K4; ++c4) {
            int c = c4 * 4;
            float wx = w[(c + 0) * 64 + lane];
            float wy = w[(c + 1) * 64 + lane];
            float wz = w[(c + 2) * 64 + lane];
            float ww = w[(c + 3) * 64 + lane];
            float4 a0v = *(const float4*)&s_agg[aoff + c];
            float4 a1v = *(const float4*)&s_agg[704 + aoff + c];
            acc0 = fmaf(a0v.x, wx, fmaf(a0v.y, wy, fmaf(a0v.z, wz, fmaf(a0v.w, ww, acc0))));
            acc1 = fmaf(a1v.x, wx, fmaf(a1v.y, wy, fmaf(a1v.z, wz, fmaf(a1v.w, ww, acc1))));
        }
        s_cout[t] = acc0;
        s_cout[256 + t] = acc1;
    }
    __syncthreads();

    #pragma unroll
    for (int n = 0; n < 2; ++n) {
        float v = s_cout[n * 256 + t];
        float g;
        if (wave == 0) {
            g = ssp_fast(v);
        } else {
            float c0 = s_cout[n * 256 + 64 + lane];
            float c1 = s_cout[n * 256 + 128 + lane];
            float c2 = s_cout[n * 256 + 192 + lane];
            g = ssp_fast(sqrtf(fmaf(c0, c0, fmaf(c1, c1, fmaf(c2, c2, 1e-12f)))));
        }
        s_gated[n * 256 + t] = v * g;
    }
    __syncthreads();

    {
        const float* w = (wave == 0) ? w_b0 : w_b1;
        int aoff = (wave == 0) ? 0 : 64 + (wave - 1) * 64;
        float acc0 = 0.f, acc1 = 0.f;
        for (int c4 = 0; c4 < 16; ++c4) {
            int c = c4 * 4;
            float wx = w[(c + 0) * 64 + lane];
            float wy = w[(c + 1) * 64 + lane];
            float wz = w[(c + 2) * 64 + lane];
            float ww = w[(c + 3) * 64 + lane];
            float4 g0 = *(const float4*)&s_gated[aoff + c];
            float4 g1 = *(const float4*)&s_gated[256 + aoff + c];
            acc0 = fmaf(g0.x, wx, fmaf(g0.y, wy, fmaf(g0.z, wz, fmaf(g0.w, ww, acc0))));
            acc1 = fmaf(g1.x, wx, fmaf(g1.y, wy, fmaf(g1.z, wz, fmaf(g1.w, ww, acc1))));
        }
        out[(size_t)i0 * 256 + t]       = feat[(size_t)i0 * 256 + t] + acc0;
        out[(size_t)(i0 + 1) * 256 + t] = feat[(size_t)(i0 + 1) * 256 + t] + acc1;
    }
}

extern "C" void kernel_launch(void* const* d_in, const int* in_sizes, int n_in,
                              void* d_out, int out_size, void* d_ws, size_t ws_size,
                              hipStream_t stream) {
    const float* xyz     = (const float*)d_in[0];
    const float* feat    = (const float*)d_in[1];
    const float* w_f1    = (const float*)d_in[2];
    const float* w_f2    = (const float*)d_in[3];
    const float* w_pre0  = (const float*)d_in[4];
    const float* w_pre1  = (const float*)d_in[5];
    const float* w_a0    = (const float*)d_in[6];
    const float* w_a1    = (const float*)d_in[7];
    const float* w_b0    = (const float*)d_in[8];
    const float* w_b1    = (const float*)d_in[9];
    const int* src_idx   = (const int*)d_in[10];
    const int* edge_mask = (const int*)d_in[11];
    float* out = (float*)d_out;

    float* pre_t = (float*)d_ws;                              // 4 MB
    short* w1t_g = (short*)((char*)d_ws + (size_t)4194304);   // 4 KB
    short* w2t_g = w1t_g + 64 * 32;                           // 8 KB

    pre_kernel<<<NN / 8, 256, 0, stream>>>(feat, w_pre0, w_pre1, pre_t,
                                           w_f1, w_f2, w1t_g, w2t_g);
    edge_kernel<<<NN / 2, 256, 0, stream>>>(xyz, feat, pre_t, w1t_g, w2t_g,
                                            w_a0, w_a1, w_b0, w_b1,
                                            src_idx, edge_mask, out);
}